// Round 9
// baseline (68.857 us; speedup 1.0000x reference)
//
#include <hip/hip_runtime.h>
#include <hip/hip_bf16.h>

#define KN 4096
#define CN 10
#define DN 128
#define BN 1000
#define LN 512
#define SB 2048   // stream blocks

typedef float f32x4 __attribute__((ext_vector_type(4)));
typedef short bf16x8 __attribute__((ext_vector_type(8)));

__device__ __forceinline__ short bf16bits(float x) {
    __hip_bfloat16 h = __float2bfloat16(x);
    return *reinterpret_cast<short*>(&h);
}
__device__ __forceinline__ float bflo(unsigned u) {  // low bf16 of packed u32
    unsigned v = u << 16;
    return *reinterpret_cast<float*>(&v);
}
__device__ __forceinline__ float bfhi(unsigned u) {  // high bf16
    unsigned v = u & 0xFFFF0000u;
    return *reinterpret_cast<float*>(&v);
}

// ---------------- K1: prep (blocks 0..511) + P = embs @ W^T (blocks 512..575) --
__global__ __launch_bounds__(256) void w2v_prep(const float* __restrict__ embs,
                                                const float* __restrict__ W,
                                                float* __restrict__ sqn,
                                                short* __restrict__ ebf,
                                                float* __restrict__ P) {
    int blk = blockIdx.x, t = threadIdx.x;
    if (blk < 512) {
        int row = t >> 5, lane = t & 31;
        int r = blk * 8 + row;
        float4 v = ((const float4*)embs)[r * 32 + lane];
        short4 s4;
        s4.x = bf16bits(v.x); s4.y = bf16bits(v.y);
        s4.z = bf16bits(v.z); s4.w = bf16bits(v.w);
        ((short4*)ebf)[r * 32 + lane] = s4;
        float ss = v.x * v.x + v.y * v.y + v.z * v.z + v.w * v.w;
        #pragma unroll
        for (int m = 16; m >= 1; m >>= 1) ss += __shfl_xor(ss, m, 64);
        if (lane == 0) sqn[r] = ss;
        return;
    }
    int pb = blk - 512;
    int r = pb * 64 + (t >> 2);
    int q = t & 3;
    const float4* er = (const float4*)(embs + (size_t)r * DN) + q * 8;
    const float4* w4 = (const float4*)W;
    float s[CN];
    #pragma unroll
    for (int c = 0; c < CN; ++c) s[c] = 0.f;
    #pragma unroll
    for (int d4 = 0; d4 < 8; ++d4) {
        float4 e = er[d4];
        #pragma unroll
        for (int c = 0; c < CN; ++c) {
            float4 w = w4[c * 32 + q * 8 + d4];
            s[c] += e.x * w.x + e.y * w.y + e.z * w.z + e.w * w.w;
        }
    }
    #pragma unroll
    for (int c = 0; c < CN; ++c) {
        s[c] += __shfl_xor(s[c], 1, 64);
        s[c] += __shfl_xor(s[c], 2, 64);
    }
    if (q == 0) {
        float* pr = P + (size_t)r * 12;
        #pragma unroll
        for (int c = 0; c < CN; ++c) pr[c] = s[c];
        pr[10] = 0.f; pr[11] = 0.f;
    }
}

// ---------------- K2: gram — dist matrix as bf16, 128x128 tile per block -------
__global__ __launch_bounds__(256, 4) void w2v_gram(const short* __restrict__ ebf,
                                                   const float* __restrict__ sqn,
                                                   short* __restrict__ dmat) {
    __shared__ short dl[128 * 128];   // 32KB dist tile
    __shared__ float sqi[128];
    __shared__ float sqj[128];

    int t  = threadIdx.x;
    int i0 = blockIdx.y * 128;
    int j0 = blockIdx.x * 128;

    if (t < 128) sqi[t] = sqn[i0 + t];
    else         sqj[t - 128] = sqn[j0 + t - 128];

    int wave = t >> 6, lane = t & 63;
    int wr = (wave >> 1) * 64;
    int wc = (wave & 1) * 64;
    int lr = lane & 15;
    int lg = lane >> 4;

    const short* Ai = ebf + (size_t)(i0 + wr + lr) * DN;
    const short* Bj = ebf + (size_t)(j0 + wc + lr) * DN;

    f32x4 acc4[4][4];
    #pragma unroll
    for (int mi = 0; mi < 4; ++mi)
        #pragma unroll
        for (int nj = 0; nj < 4; ++nj)
            acc4[mi][nj] = (f32x4){0.f, 0.f, 0.f, 0.f};

    #pragma unroll
    for (int kk = 0; kk < 4; ++kk) {
        int ko = kk * 32 + lg * 8;
        bf16x8 afr[4], bfr[4];
        #pragma unroll
        for (int mi = 0; mi < 4; ++mi) {
            afr[mi] = *(const bf16x8*)(Ai + (size_t)mi * 16 * DN + ko);
            bfr[mi] = *(const bf16x8*)(Bj + (size_t)mi * 16 * DN + ko);
        }
        #pragma unroll
        for (int mi = 0; mi < 4; ++mi)
            #pragma unroll
            for (int nj = 0; nj < 4; ++nj)
                acc4[mi][nj] = __builtin_amdgcn_mfma_f32_16x16x32_bf16(
                    afr[mi], bfr[nj], acc4[mi][nj], 0, 0, 0);
    }

    __syncthreads();   // sqi/sqj visible

    // dist -> bf16 -> LDS tile
    #pragma unroll
    for (int mi = 0; mi < 4; ++mi) {
        #pragma unroll
        for (int v = 0; v < 4; ++v) {
            int row = wr + 16 * mi + lg * 4 + v;
            float si = sqi[row];
            #pragma unroll
            for (int nj = 0; nj < 4; ++nj) {
                int col = wc + 16 * nj + lr;
                float sq = fmaxf(si + sqj[col] - 2.f * acc4[mi][nj][v], 0.f);
                dl[row * 128 + col] = bf16bits(sqrtf(sq));
            }
        }
    }
    __syncthreads();

    // coalesced write-out: 2048 uint4, 8 per thread
    const uint4* s4 = (const uint4*)dl;
    #pragma unroll
    for (int k = 0; k < 8; ++k) {
        int idx  = k * 256 + t;
        int row  = idx >> 4;
        int colq = idx & 15;
        ((uint4*)(dmat + (size_t)(i0 + row) * KN + j0))[colq] = s4[idx];
    }
}

// ---------------- K3: stream (blocks 0..2047) + sup (2048..3047) ---------------
__global__ __launch_bounds__(256) void w2v_stream(const float* __restrict__ pc,
                                                  const short* __restrict__ dmat,
                                                  const float* __restrict__ P,
                                                  const int* __restrict__ reads,
                                                  const int* __restrict__ labels,
                                                  float* __restrict__ psup,
                                                  float* __restrict__ puns) {
    __shared__ float wred[4];
    int blk = blockIdx.x, t = threadIdx.x;

    if (blk < SB) {
        // copy-shaped: 4 iters x 8 elements, all 12 loads issued up front
        float4 pa[4], pb[4];
        uint4  dv[4];
        #pragma unroll
        for (int it = 0; it < 4; ++it) {
            size_t q = ((size_t)(it * SB + blk)) * 256 + t;   // uint4 index
            pa[it] = ((const float4*)pc)[2 * q];
            pb[it] = ((const float4*)pc)[2 * q + 1];
            dv[it] = ((const uint4*)dmat)[q];
        }
        float part = 0.f;
        #pragma unroll
        for (int it = 0; it < 4; ++it) {
            float p[8] = { pa[it].x, pa[it].y, pa[it].z, pa[it].w,
                           pb[it].x, pb[it].y, pb[it].z, pb[it].w };
            float d[8] = { bflo(dv[it].x), bfhi(dv[it].x),
                           bflo(dv[it].y), bfhi(dv[it].y),
                           bflo(dv[it].z), bfhi(dv[it].z),
                           bflo(dv[it].w), bfhi(dv[it].w) };
            #pragma unroll
            for (int e = 0; e < 8; ++e) {
                float tt = fmaf(p[e], d[e], __expf(-d[e]));
                part += (p[e] != 0.f) ? tt : 0.f;
            }
        }
        #pragma unroll
        for (int off = 32; off > 0; off >>= 1) part += __shfl_down(part, off, 64);
        int lane = t & 63, wave = t >> 6;
        if (lane == 0) wred[wave] = part;
        __syncthreads();
        if (t == 0)
            puns[blk] = (wred[0] + wred[1]) + (wred[2] + wred[3]);
        return;
    }

    // ---- supervised via P-gather, wave 0 only ----
    if (t >= 64) return;
    int b = blk - SB;
    const int4* rr = (const int4*)(reads + (size_t)b * LN);
    int4 r0 = rr[t * 2], r1 = rr[t * 2 + 1];
    int idx[8] = { r0.x, r0.y, r0.z, r0.w, r1.x, r1.y, r1.z, r1.w };
    const float4* P4 = (const float4*)P;
    float s[12];
    #pragma unroll
    for (int i = 0; i < 12; ++i) s[i] = 0.f;
    #pragma unroll
    for (int k = 0; k < 8; ++k) {
        size_t o = (size_t)idx[k] * 3;
        float4 x = P4[o], y = P4[o + 1], z = P4[o + 2];
        s[0] += x.x; s[1] += x.y; s[2]  += x.z; s[3]  += x.w;
        s[4] += y.x; s[5] += y.y; s[6]  += y.z; s[7]  += y.w;
        s[8] += z.x; s[9] += z.y; s[10] += z.z; s[11] += z.w;
    }
    #pragma unroll
    for (int off = 32; off > 0; off >>= 1)
        #pragma unroll
        for (int i = 0; i < CN; ++i) s[i] += __shfl_down(s[i], off, 64);
    if (t == 0) {
        float m = s[0];
        #pragma unroll
        for (int c = 1; c < CN; ++c) m = fmaxf(m, s[c]);
        float se = 0.f;
        #pragma unroll
        for (int c = 0; c < CN; ++c) se += __expf(s[c] - m);
        float lse = m + __logf(se);
        psup[b] = -(s[labels[b]] - lse);
    }
}

// ---------------- K4: final reduce + combine -----------------------------------
__global__ __launch_bounds__(256) void w2v_final(const float* __restrict__ psup,
                                                 const float* __restrict__ puns,
                                                 const float* __restrict__ delta,
                                                 float* __restrict__ out) {
    __shared__ float r1[4], r2[4];
    int t = threadIdx.x;
    float a = 0.f, bsum = 0.f;
    for (int i = t; i < BN; i += 256)  a += psup[i];
    for (int i = t; i < SB; i += 256)  bsum += puns[i];
    #pragma unroll
    for (int off = 32; off > 0; off >>= 1) {
        a += __shfl_down(a, off, 64);
        bsum += __shfl_down(bsum, off, 64);
    }
    int lane = t & 63, wave = t >> 6;
    if (lane == 0) { r1[wave] = a; r2[wave] = bsum; }
    __syncthreads();
    if (t == 0) {
        float sup = (r1[0] + r1[1]) + (r1[2] + r1[3]);
        float uns = ((r2[0] + r2[1]) + (r2[2] + r2[3])) * (1.f / 16777216.f);
        float d = delta[0];
        out[0] = d * sup + (1.f - d) * uns;
    }
}

extern "C" void kernel_launch(void* const* d_in, const int* in_sizes, int n_in,
                              void* d_out, int out_size, void* d_ws, size_t ws_size,
                              hipStream_t stream) {
    const float* pc     = (const float*)d_in[0];
    const int*   reads  = (const int*)  d_in[1];
    const int*   labels = (const int*)  d_in[2];
    const float* delta  = (const float*)d_in[3];
    const float* embs   = (const float*)d_in[4];
    const float* W      = (const float*)d_in[5];
    float* out = (float*)d_out;

    char* ws = (char*)d_ws;
    float* sqn  = (float*)ws;                 // 4096 f32           @ 0
    float* P    = (float*)(ws + 16384);       // 4096x12 f32        @ 16384
    short* ebf  = (short*)(ws + 212992);      // 4096x128 bf16      @ 212992
    float* psup = (float*)(ws + 1261568);     // 1000 f32
    float* puns = (float*)(ws + 1265664);     // 2048 f32
    short* dmat = (short*)(ws + 1277952);     // 4096x4096 bf16 (33.5 MB)

    w2v_prep<<<576, 256, 0, stream>>>(embs, W, sqn, ebf, P);
    w2v_gram<<<dim3(32, 32), 256, 0, stream>>>(ebf, sqn, dmat);
    w2v_stream<<<SB + BN, 256, 0, stream>>>(pc, dmat, P, reads, labels, psup, puns);
    w2v_final<<<1, 256, 0, stream>>>(psup, puns, delta, out);
}